// Round 5
// baseline (225.966 us; speedup 1.0000x reference)
//
#include <hip/hip_runtime.h>
#include <math.h>

#define FDIM 128
#define AVG_D_LOGF 2.6f
#define BN_EPS 1e-5f

using f32x4 = __attribute__((ext_vector_type(4))) float;
using s16x8 = __attribute__((ext_vector_type(8))) short;
using u16x8 = __attribute__((ext_vector_type(8))) unsigned short;

__device__ __forceinline__ unsigned short f2bf(float x) {
  unsigned int u = __float_as_uint(x);
  u += 0x7FFFu + ((u >> 16) & 1u);   // RNE; inputs are finite
  return (unsigned short)(u >> 16);
}
__device__ __forceinline__ float bf2f(unsigned short u) {
  return __uint_as_float(((unsigned int)u) << 16);
}

// ---------------- fused prep: h->bf16, W->bf16 transposed, degree count ----------------
__global__ void prep_kernel(const float* __restrict__ h, unsigned short* __restrict__ hb,
                            const float* __restrict__ W, unsigned short* __restrict__ wBT,
                            const int* __restrict__ dst, int* __restrict__ deg,
                            int w0, int w1, int w2, int K) {
  int i = blockIdx.x * 256 + threadIdx.x;
  if (i < w0) {                       // conv_h: 8 elems per thread
    const f32x4* sp = (const f32x4*)h + (size_t)i * 2;
    f32x4 v0 = sp[0], v1 = sp[1];
    u16x8 o;
    o[0] = f2bf(v0[0]); o[1] = f2bf(v0[1]); o[2] = f2bf(v0[2]); o[3] = f2bf(v0[3]);
    o[4] = f2bf(v1[0]); o[5] = f2bf(v1[1]); o[6] = f2bf(v1[2]); o[7] = f2bf(v1[3]);
    *((u16x8*)hb + i) = o;
  } else if (i < w0 + w1) {           // conv_wt: 1 elem per thread
    int idx = i - w0;
    int k = idx >> 7, j = idx & 127;
    wBT[(size_t)j * K + k] = f2bf(W[idx]);
  } else if (i < w0 + w1 + w2) {      // degree count
    atomicAdd(&deg[dst[i - w0 - w1]], 1);
  }
}

// ---------------- CSR build (block-local scan; bsums folded into consumers) ----------------
__global__ void scan1(const int* __restrict__ deg, int* __restrict__ offs,
                      int* __restrict__ bsums, int n) {
  __shared__ int tmp[256];
  int t = threadIdx.x, i = blockIdx.x * 256 + t;
  int v = (i < n) ? deg[i] : 0;
  tmp[t] = v; __syncthreads();
  for (int d = 1; d < 256; d <<= 1) {
    int x = (t >= d) ? tmp[t - d] : 0;
    __syncthreads();
    tmp[t] += x;
    __syncthreads();
  }
  if (i < n) offs[i] = tmp[t] - v;
  if (t == 255) bsums[blockIdx.x] = tmp[255];
}

__global__ void scan2(int* __restrict__ bsums, int nb) {
  __shared__ int tmp[256];
  int t = threadIdx.x;
  int v = (t < nb) ? bsums[t] : 0;
  tmp[t] = v; __syncthreads();
  for (int d = 1; d < 256; d <<= 1) {
    int x = (t >= d) ? tmp[t - d] : 0;
    __syncthreads();
    tmp[t] += x;
    __syncthreads();
  }
  if (t < nb) bsums[t] = tmp[t] - v;
}

__global__ void csr_fill(const int* __restrict__ src, const int* __restrict__ dst,
                         const int* __restrict__ offs, const int* __restrict__ bsums,
                         int* __restrict__ cursor, int* __restrict__ csr, int E) {
  int i = blockIdx.x * 256 + threadIdx.x;
  if (i < E) {
    int d = dst[i];
    int pos = offs[d] + bsums[d >> 8] + atomicAdd(&cursor[d], 1);
    csr[pos] = src[i];
  }
}

// ---------------- per-node aggregation (one wave per node, bf16 gather) ----------------
__global__ __launch_bounds__(256) void agg_kernel(
    const unsigned short* __restrict__ hb, const int* __restrict__ csr,
    const int* __restrict__ offs, const int* __restrict__ bsums,
    unsigned short* __restrict__ aggb, float2* __restrict__ s12a, int n, int E) {
  const int gw = (blockIdx.x * 256 + threadIdx.x) >> 6;
  const int lane = threadIdx.x & 63;
  if (gw >= n) return;
  const int beg = offs[gw] + bsums[gw >> 8];
  const int end = (gw + 1 < n) ? offs[gw + 1] + bsums[(gw + 1) >> 8] : E;
  const unsigned int* hp = (const unsigned int*)hb;    // 2 bf16 per uint, 64 uints/row
  float s0 = 0.f, s1 = 0.f, q0 = 0.f, q1 = 0.f;
  float mx0 = -INFINITY, mx1 = -INFINITY, mn0 = INFINITY, mn1 = INFINITY;
  int e = beg;
  for (; e + 4 <= end; e += 4) {
    int i0 = csr[e], i1 = csr[e + 1], i2 = csr[e + 2], i3 = csr[e + 3];
    unsigned int a = hp[(size_t)i0 * 64 + lane];
    unsigned int b = hp[(size_t)i1 * 64 + lane];
    unsigned int c = hp[(size_t)i2 * 64 + lane];
    unsigned int d = hp[(size_t)i3 * 64 + lane];
    float a0 = bf2f((unsigned short)a), a1 = bf2f((unsigned short)(a >> 16));
    float b0 = bf2f((unsigned short)b), b1 = bf2f((unsigned short)(b >> 16));
    float c0 = bf2f((unsigned short)c), c1 = bf2f((unsigned short)(c >> 16));
    float d0 = bf2f((unsigned short)d), d1 = bf2f((unsigned short)(d >> 16));
    s0 += (a0 + b0) + (c0 + d0); s1 += (a1 + b1) + (c1 + d1);
    q0 += (a0 * a0 + b0 * b0) + (c0 * c0 + d0 * d0);
    q1 += (a1 * a1 + b1 * b1) + (c1 * c1 + d1 * d1);
    mx0 = fmaxf(fmaxf(mx0, a0), fmaxf(b0, fmaxf(c0, d0)));
    mx1 = fmaxf(fmaxf(mx1, a1), fmaxf(b1, fmaxf(c1, d1)));
    mn0 = fminf(fminf(mn0, a0), fminf(b0, fminf(c0, d0)));
    mn1 = fminf(fminf(mn1, a1), fminf(b1, fminf(c1, d1)));
  }
  for (; e < end; ++e) {
    int i0 = csr[e];
    unsigned int a = hp[(size_t)i0 * 64 + lane];
    float a0 = bf2f((unsigned short)a), a1 = bf2f((unsigned short)(a >> 16));
    s0 += a0; s1 += a1;
    q0 += a0 * a0; q1 += a1 * a1;
    mx0 = fmaxf(mx0, a0); mx1 = fmaxf(mx1, a1);
    mn0 = fminf(mn0, a0); mn1 = fminf(mn1, a1);
  }
  float degf = (float)(end - beg);
  if (degf < 1.f) degf = 1.f;
  const float inv = 1.f / degf;
  float me0 = s0 * inv, me1 = s1 * inv;
  float v0 = q0 * inv - me0 * me0, v1 = q1 * inv - me1 * me1;
  float st0 = sqrtf(fmaxf(v0, 0.f) + BN_EPS);
  float st1 = sqrtf(fmaxf(v1, 0.f) + BN_EPS);
  unsigned int base = (unsigned int)gw * 512u + (unsigned int)lane * 2u;
  *(unsigned int*)&aggb[base      ] = (unsigned int)f2bf(me0) | ((unsigned int)f2bf(me1) << 16);
  *(unsigned int*)&aggb[base + 128] = (unsigned int)f2bf(mx0) | ((unsigned int)f2bf(mx1) << 16);
  *(unsigned int*)&aggb[base + 256] = (unsigned int)f2bf(mn0) | ((unsigned int)f2bf(mn1) << 16);
  *(unsigned int*)&aggb[base + 384] = (unsigned int)f2bf(st0) | ((unsigned int)f2bf(st1) << 16);
  if (lane == 0) {
    float logd = logf(degf + 1.f);
    s12a[gw] = make_float2(logd / AVG_D_LOGF, AVG_D_LOGF / logd);
  }
}

// ---------------- fused GEMM, NO LDS: all MFMA fragments loaded straight from
// global (L1/L2-resident). Zero barriers, zero waitcnt drains; the compiler
// free-schedules loads against MFMAs and ~3 blocks/CU hide the rest.
// out = relu(h@W0 + agg@W1 + s1*(agg@W2) + s2*(agg@W3) + b), fused BN sums.
__global__ __launch_bounds__(256) void gemm_kernel(
    const unsigned short* __restrict__ hb, const unsigned short* __restrict__ wBT,
    const unsigned short* __restrict__ aggb, const float2* __restrict__ s12a,
    const float* __restrict__ bias, float* __restrict__ out,
    float* __restrict__ bnsum, float* __restrict__ bnsq, int n, int K) {
  __shared__ float red[128];
  const int t = threadIdx.x;
  const int lane = t & 63;
  const int w = t >> 6;
  const int wr = w >> 1, wc = w & 1;
  const int hi = lane >> 4, lr = lane & 15;

  // bijective XCD-chunked swizzle (m204)
  const int nwg = gridDim.x;
  const int q = nwg >> 3, r = nwg & 7;
  const int xcd = blockIdx.x & 7, jj = blockIdx.x >> 3;
  const int bx = (xcd < r ? xcd * (q + 1) : r * (q + 1) + (xcd - r) * q) + jj;

  const int m0 = (bx >> 1) * 128;
  const int n0 = (bx & 1) * 64;

  f32x4 acc[3][4][2] = {};

  const unsigned short* aH[4];
  const unsigned short* aG[4];
  #pragma unroll
  for (int m = 0; m < 4; ++m) {
    int row = m0 + wr * 64 + m * 16 + lr;
    if (row >= n) row = n - 1;
    aH[m] = hb   + (size_t)row * FDIM + hi * 8;
    aG[m] = aggb + (size_t)row * 512  + hi * 8;
  }
  const unsigned short* bP[2];
  #pragma unroll
  for (int nn = 0; nn < 2; ++nn)
    bP[nn] = wBT + (size_t)(n0 + wc * 32 + nn * 16 + lr) * K + hi * 8;

  // ---- phase 1: h section (W rows 0..127), acc[0] only ----
  #pragma unroll
  for (int step = 0; step < 2; ++step) {
    const int kg = step * 64;
    s16x8 a[2][4], b[2][2];
    #pragma unroll
    for (int ks = 0; ks < 2; ++ks) {
      #pragma unroll
      for (int m = 0; m < 4; ++m) a[ks][m] = *(const s16x8*)(aH[m] + kg + ks * 32);
      #pragma unroll
      for (int nn = 0; nn < 2; ++nn) b[ks][nn] = *(const s16x8*)(bP[nn] + kg + ks * 32);
    }
    #pragma unroll
    for (int ks = 0; ks < 2; ++ks)
      #pragma unroll
      for (int m = 0; m < 4; ++m)
        #pragma unroll
        for (int nn = 0; nn < 2; ++nn)
          acc[0][m][nn] = __builtin_amdgcn_mfma_f32_16x16x32_bf16(a[ks][m], b[ks][nn],
                                                                  acc[0][m][nn], 0, 0, 0);
  }

  // ---- phase 2: agg section (8 K-steps of 64), three W sections ----
  for (int step = 0; step < 8; ++step) {
    const int kg = step * 64;
    s16x8 a[2][4];
    #pragma unroll
    for (int ks = 0; ks < 2; ++ks)
      #pragma unroll
      for (int m = 0; m < 4; ++m) a[ks][m] = *(const s16x8*)(aG[m] + kg + ks * 32);
    #pragma unroll
    for (int s = 0; s < 3; ++s) {
      const int koff = FDIM + s * 512 + kg;
      s16x8 b[2][2];
      #pragma unroll
      for (int ks = 0; ks < 2; ++ks)
        #pragma unroll
        for (int nn = 0; nn < 2; ++nn)
          b[ks][nn] = *(const s16x8*)(bP[nn] + koff + ks * 32);
      #pragma unroll
      for (int ks = 0; ks < 2; ++ks)
        #pragma unroll
        for (int m = 0; m < 4; ++m)
          #pragma unroll
          for (int nn = 0; nn < 2; ++nn)
            acc[s][m][nn] = __builtin_amdgcn_mfma_f32_16x16x32_bf16(a[ks][m], b[ks][nn],
                                                                    acc[s][m][nn], 0, 0, 0);
    }
  }

  // ---- epilogue: combine, bias, relu, store; fused BN partial sums ----
  if (t < 128) red[t] = 0.f;
  __syncthreads();

  const float bv0 = bias[n0 + wc * 32 + lr];
  const float bv1 = bias[n0 + wc * 32 + 16 + lr];
  float cs[2] = {0.f, 0.f}, cq[2] = {0.f, 0.f};
  #pragma unroll
  for (int m = 0; m < 4; ++m) {
    #pragma unroll
    for (int i = 0; i < 4; ++i) {
      int grow = m0 + wr * 64 + m * 16 + hi * 4 + i;
      if (grow >= n) continue;
      float2 sv = s12a[grow];
      #pragma unroll
      for (int nn = 0; nn < 2; ++nn) {
        float v = acc[0][m][nn][i] + sv.x * acc[1][m][nn][i] + sv.y * acc[2][m][nn][i]
                + (nn ? bv1 : bv0);
        v = fmaxf(v, 0.f);
        out[(size_t)grow * FDIM + n0 + wc * 32 + nn * 16 + lr] = v;
        cs[nn] += v; cq[nn] += v * v;
      }
    }
  }
  #pragma unroll
  for (int nn = 0; nn < 2; ++nn) {
    int lc = wc * 32 + nn * 16 + lr;
    atomicAdd(&red[lc], cs[nn]);
    atomicAdd(&red[64 + lc], cq[nn]);
  }
  __syncthreads();
  if (t < 64)       atomicAdd(&bnsum[n0 + t], red[t]);
  else if (t < 128) atomicAdd(&bnsq[n0 + t - 64], red[t]);
}

// ---------------- BatchNorm apply ----------------
__global__ void bn_norm(float* __restrict__ out, const float* __restrict__ bnsum,
                        const float* __restrict__ bnsq, const float* __restrict__ gamma,
                        const float* __restrict__ beta, int n) {
  const int j = threadIdx.x & 127;
  const float invN = 1.f / (float)n;
  const float mu = bnsum[j] * invN;
  const float var = bnsq[j] * invN - mu * mu;
  const float rs = rsqrtf(var + BN_EPS);
  const float sc = gamma[j] * rs;
  const float sh = beta[j] - mu * sc;
  const int gt = blockIdx.x * 256 + threadIdx.x;
  const int row0 = gt >> 7;
  const int rstride = (gridDim.x * 256) >> 7;
  for (int i = row0; i < n; i += rstride) {
    size_t idx = (size_t)i * FDIM + j;
    out[idx] = out[idx] * sc + sh;
  }
}

extern "C" void kernel_launch(void* const* d_in, const int* in_sizes, int n_in,
                              void* d_out, int out_size, void* d_ws, size_t ws_size,
                              hipStream_t stream) {
  const float* h     = (const float*)d_in[0];
  const int*   src   = (const int*)d_in[1];
  const int*   dst   = (const int*)d_in[2];
  const float* W     = (const float*)d_in[3];
  const float* bias  = (const float*)d_in[4];
  const float* gamma = (const float*)d_in[5];
  const float* beta  = (const float*)d_in[6];
  float* out = (float*)d_out;

  const int n = in_sizes[0] / FDIM;      // 50000
  const int E = in_sizes[1];             // 650000
  const int K = in_sizes[3] / FDIM;      // 1664

  char* base = (char*)d_ws;
  size_t off = 0;
  auto alloc = [&](size_t bytes) -> void* {
    void* p = base + off;
    off += (bytes + 255) & ~(size_t)255;
    return p;
  };
  int*   deg    = (int*)  alloc(4ull * n);
  int*   cursor = (int*)  alloc(4ull * n);
  float* bnsum  = (float*)alloc(512);
  float* bnsq   = (float*)alloc(512);
  const size_t zlen = off;               // zero deg+cursor+bn each call
  int*    offs  = (int*)  alloc(4ull * (n + 1));
  int*    bsums = (int*)  alloc(4ull * 256);
  int*    csr   = (int*)  alloc(4ull * E);
  float2* s12a  = (float2*)alloc(8ull * n);
  unsigned short* aggb = (unsigned short*)alloc(2ull * (size_t)n * 512);
  unsigned short* wBT  = (unsigned short*)alloc(2ull * (size_t)K * FDIM);
  unsigned short* hb   = (unsigned short*)alloc(2ull * (size_t)n * FDIM);
  (void)ws_size; (void)n_in; (void)out_size;

  const int eb = (E + 255) / 256;
  const int nb = (n + 255) / 256;
  const int w0 = n * FDIM / 8;           // conv_h work items
  const int w1 = K * FDIM;               // conv_wt work items
  const int w2 = E;                      // deg work items

  hipMemsetAsync(d_ws, 0, zlen, stream);
  prep_kernel<<<(w0 + w1 + w2 + 255) / 256, 256, 0, stream>>>(h, hb, W, wBT, dst, deg,
                                                              w0, w1, w2, K);
  scan1<<<nb, 256, 0, stream>>>(deg, offs, bsums, n);
  scan2<<<1, 256, 0, stream>>>(bsums, nb);
  csr_fill<<<eb, 256, 0, stream>>>(src, dst, offs, bsums, cursor, csr, E);
  agg_kernel<<<(n + 3) / 4, 256, 0, stream>>>(hb, csr, offs, bsums, aggb, s12a, n, E);
  const int gblocks = ((n + 127) / 128) * 2;
  gemm_kernel<<<gblocks, 256, 0, stream>>>(hb, wBT, aggb, s12a, bias,
                                           out, bnsum, bnsq, n, K);
  bn_norm<<<1024, 256, 0, stream>>>(out, bnsum, bnsq, gamma, beta, n);
}

// Round 6
// 184.126 us; speedup vs baseline: 1.2272x; 1.2272x over previous
//
#include <hip/hip_runtime.h>
#include <math.h>

#define FDIM 128
#define AVG_D_LOGF 2.6f
#define BN_EPS 1e-5f
#define NK 10          // K-steps: 2 (h section) + 8 (agg section)

using f32x4 = __attribute__((ext_vector_type(4))) float;
using s16x8 = __attribute__((ext_vector_type(8))) short;
using u16x8 = __attribute__((ext_vector_type(8))) unsigned short;

__device__ __forceinline__ unsigned short f2bf(float x) {
  unsigned int u = __float_as_uint(x);
  u += 0x7FFFu + ((u >> 16) & 1u);   // RNE; inputs are finite
  return (unsigned short)(u >> 16);
}
__device__ __forceinline__ float bf2f(unsigned short u) {
  return __uint_as_float(((unsigned int)u) << 16);
}

__device__ __forceinline__ void gload16(const void* g, void* l) {
  __builtin_amdgcn_global_load_lds(
      (const __attribute__((address_space(1))) void*)g,
      (__attribute__((address_space(3))) void*)l, 16, 0, 0);
}

// ---------------- fused prep: h->bf16, W->bf16 transposed, degree count ----------------
__global__ void prep_kernel(const float* __restrict__ h, unsigned short* __restrict__ hb,
                            const float* __restrict__ W, unsigned short* __restrict__ wBT,
                            const int* __restrict__ dst, int* __restrict__ deg,
                            int w0, int w1, int w2, int K) {
  int i = blockIdx.x * 256 + threadIdx.x;
  if (i < w0) {                       // conv_h: 8 elems per thread
    const f32x4* sp = (const f32x4*)h + (size_t)i * 2;
    f32x4 v0 = sp[0], v1 = sp[1];
    u16x8 o;
    o[0] = f2bf(v0[0]); o[1] = f2bf(v0[1]); o[2] = f2bf(v0[2]); o[3] = f2bf(v0[3]);
    o[4] = f2bf(v1[0]); o[5] = f2bf(v1[1]); o[6] = f2bf(v1[2]); o[7] = f2bf(v1[3]);
    *((u16x8*)hb + i) = o;
  } else if (i < w0 + w1) {           // conv_wt: 1 elem per thread
    int idx = i - w0;
    int k = idx >> 7, j = idx & 127;
    wBT[(size_t)j * K + k] = f2bf(W[idx]);
  } else if (i < w0 + w1 + w2) {      // degree count
    atomicAdd(&deg[dst[i - w0 - w1]], 1);
  }
}

// ---------------- CSR build: block-local scan; consumers recompute bsums prefix ----------------
__global__ void scan1(const int* __restrict__ deg, int* __restrict__ offs,
                      int* __restrict__ bsums, int n) {
  __shared__ int tmp[256];
  int t = threadIdx.x, i = blockIdx.x * 256 + t;
  int v = (i < n) ? deg[i] : 0;
  tmp[t] = v; __syncthreads();
  for (int d = 1; d < 256; d <<= 1) {
    int x = (t >= d) ? tmp[t - d] : 0;
    __syncthreads();
    tmp[t] += x;
    __syncthreads();
  }
  if (i < n) offs[i] = tmp[t] - v;
  if (t == 255) bsums[blockIdx.x] = tmp[255];
}

__global__ void csr_fill(const int* __restrict__ src, const int* __restrict__ dst,
                         const int* __restrict__ offs, const int* __restrict__ bsums,
                         int* __restrict__ cursor, int* __restrict__ csr, int E, int nb) {
  __shared__ int tmp[256];
  __shared__ int ex[256];
  const int t = threadIdx.x;
  {
    int v = (t < nb) ? bsums[t] : 0;
    tmp[t] = v; __syncthreads();
    for (int d = 1; d < 256; d <<= 1) {
      int x = (t >= d) ? tmp[t - d] : 0;
      __syncthreads();
      tmp[t] += x;
      __syncthreads();
    }
    ex[t] = tmp[t] - v;
    __syncthreads();
  }
  int i = blockIdx.x * 256 + t;
  if (i < E) {
    int d = dst[i];
    int pos = offs[d] + ex[d >> 8] + atomicAdd(&cursor[d], 1);
    csr[pos] = src[i];
  }
}

// ---------------- per-node aggregation: one wave per node, 2 edges per wave,
// 8B (uint2 = 4 bf16) per lane; halves gather-instruction count vs 4B/lane.
__global__ __launch_bounds__(256) void agg_kernel(
    const unsigned short* __restrict__ hb, const int* __restrict__ csr,
    const int* __restrict__ offs, const int* __restrict__ bsums,
    unsigned short* __restrict__ aggb, float2* __restrict__ s12a,
    int n, int E, int nb) {
  __shared__ int tmp[256];
  __shared__ int ex[256];
  {
    int t = threadIdx.x;
    int v = (t < nb) ? bsums[t] : 0;
    tmp[t] = v; __syncthreads();
    for (int d = 1; d < 256; d <<= 1) {
      int x = (t >= d) ? tmp[t - d] : 0;
      __syncthreads();
      tmp[t] += x;
      __syncthreads();
    }
    ex[t] = tmp[t] - v;
    __syncthreads();
  }
  const int gw = (blockIdx.x * 256 + threadIdx.x) >> 6;
  const int lane = threadIdx.x & 63;
  if (gw >= n) return;
  const int beg = offs[gw] + ex[gw >> 8];
  const int end = (gw + 1 < n) ? offs[gw + 1] + ex[(gw + 1) >> 8] : E;
  const int sub = lane >> 5;          // which edge of the pair
  const int fl  = lane & 31;          // features 4*fl .. 4*fl+3
  const uint2* hp2 = (const uint2*)hb;   // 32 uint2 per 128-feature row

  float s0=0.f,s1=0.f,s2=0.f,s3=0.f, q0=0.f,q1=0.f,q2=0.f,q3=0.f;
  float mx0=-INFINITY,mx1=-INFINITY,mx2=-INFINITY,mx3=-INFINITY;
  float mn0=INFINITY,mn1=INFINITY,mn2=INFINITY,mn3=INFINITY;

  auto acc1 = [&](uint2 A) {
    float a0 = bf2f((unsigned short)A.x), a1 = bf2f((unsigned short)(A.x >> 16));
    float a2 = bf2f((unsigned short)A.y), a3 = bf2f((unsigned short)(A.y >> 16));
    s0 += a0; s1 += a1; s2 += a2; s3 += a3;
    q0 += a0*a0; q1 += a1*a1; q2 += a2*a2; q3 += a3*a3;
    mx0 = fmaxf(mx0,a0); mx1 = fmaxf(mx1,a1); mx2 = fmaxf(mx2,a2); mx3 = fmaxf(mx3,a3);
    mn0 = fminf(mn0,a0); mn1 = fminf(mn1,a1); mn2 = fminf(mn2,a2); mn3 = fminf(mn3,a3);
  };

  const int cnt = end - beg;
  const int pairs = cnt >> 1;
  int p = 0;
  for (; p + 4 <= pairs; p += 4) {
    int base = beg + 2 * p + sub;
    int i0 = csr[base], i1 = csr[base + 2], i2 = csr[base + 4], i3 = csr[base + 6];
    uint2 A = hp2[(size_t)i0 * 32 + fl];
    uint2 B = hp2[(size_t)i1 * 32 + fl];
    uint2 C = hp2[(size_t)i2 * 32 + fl];
    uint2 D = hp2[(size_t)i3 * 32 + fl];
    acc1(A); acc1(B); acc1(C); acc1(D);
  }
  for (; p < pairs; ++p) {
    int i0 = csr[beg + 2 * p + sub];
    acc1(hp2[(size_t)i0 * 32 + fl]);
  }
  if ((cnt & 1) && sub == 0) {        // odd leftover edge: even-stream lanes only
    int i0 = csr[end - 1];
    acc1(hp2[(size_t)i0 * 32 + fl]);
  }

  // merge the two edge-streams (lane ^ 32)
  s0 += __shfl_xor(s0, 32); s1 += __shfl_xor(s1, 32);
  s2 += __shfl_xor(s2, 32); s3 += __shfl_xor(s3, 32);
  q0 += __shfl_xor(q0, 32); q1 += __shfl_xor(q1, 32);
  q2 += __shfl_xor(q2, 32); q3 += __shfl_xor(q3, 32);
  mx0 = fmaxf(mx0, __shfl_xor(mx0, 32)); mx1 = fmaxf(mx1, __shfl_xor(mx1, 32));
  mx2 = fmaxf(mx2, __shfl_xor(mx2, 32)); mx3 = fmaxf(mx3, __shfl_xor(mx3, 32));
  mn0 = fminf(mn0, __shfl_xor(mn0, 32)); mn1 = fminf(mn1, __shfl_xor(mn1, 32));
  mn2 = fminf(mn2, __shfl_xor(mn2, 32)); mn3 = fminf(mn3, __shfl_xor(mn3, 32));

  float degf = (float)cnt;
  if (degf < 1.f) degf = 1.f;
  const float inv = 1.f / degf;
  if (sub == 0) {
    float me0 = s0*inv, me1 = s1*inv, me2 = s2*inv, me3 = s3*inv;
    float st0 = sqrtf(fmaxf(q0*inv - me0*me0, 0.f) + BN_EPS);
    float st1 = sqrtf(fmaxf(q1*inv - me1*me1, 0.f) + BN_EPS);
    float st2 = sqrtf(fmaxf(q2*inv - me2*me2, 0.f) + BN_EPS);
    float st3 = sqrtf(fmaxf(q3*inv - me3*me3, 0.f) + BN_EPS);
    unsigned int b = (unsigned int)gw * 512u + (unsigned int)fl * 4u;
    uint2 wme = make_uint2((unsigned int)f2bf(me0) | ((unsigned int)f2bf(me1) << 16),
                           (unsigned int)f2bf(me2) | ((unsigned int)f2bf(me3) << 16));
    uint2 wmx = make_uint2((unsigned int)f2bf(mx0) | ((unsigned int)f2bf(mx1) << 16),
                           (unsigned int)f2bf(mx2) | ((unsigned int)f2bf(mx3) << 16));
    uint2 wmn = make_uint2((unsigned int)f2bf(mn0) | ((unsigned int)f2bf(mn1) << 16),
                           (unsigned int)f2bf(mn2) | ((unsigned int)f2bf(mn3) << 16));
    uint2 wst = make_uint2((unsigned int)f2bf(st0) | ((unsigned int)f2bf(st1) << 16),
                           (unsigned int)f2bf(st2) | ((unsigned int)f2bf(st3) << 16));
    *(uint2*)&aggb[b      ] = wme;
    *(uint2*)&aggb[b + 128] = wmx;
    *(uint2*)&aggb[b + 256] = wmn;
    *(uint2*)&aggb[b + 384] = wst;
  }
  if (lane == 0) {
    float logd = logf(degf + 1.f);
    s12a[gw] = make_float2(logd / AVG_D_LOGF, AVG_D_LOGF / logd);
  }
}

// ---------------- fused GEMM (round-3 structure, known-good ~51.5us):
// out = relu(h@W0 + agg@W1 + s1*(agg@W2) + s2*(agg@W3) + b)
// BM=128, BN=64; single-buffer LDS (40 KB) via global_load_lds + source XOR swizzle.
__global__ __launch_bounds__(256, 3) void gemm_kernel(
    const unsigned short* __restrict__ hb, const unsigned short* __restrict__ wBT,
    const unsigned short* __restrict__ aggb, const float2* __restrict__ s12a,
    const float* __restrict__ bias, float* __restrict__ out,
    float* __restrict__ bnsum, float* __restrict__ bnsq, int n, int K) {
  __shared__ s16x8 As[1024];      // 128 rows x 8 units (16B each) = 16 KB
  __shared__ s16x8 Bs[3][512];    // 3 x 64 rows x 8 units = 24 KB
  const int t = threadIdx.x;
  const int lane = t & 63;
  const int w = t >> 6;
  const int wr = w >> 1, wc = w & 1;
  const int hi = lane >> 4, lr = lane & 15, rx7 = lr & 7;

  // bijective XCD-chunked swizzle (m204)
  const int nwg = gridDim.x;
  const int q = nwg >> 3, r = nwg & 7;
  const int xcd = blockIdx.x & 7, jj = blockIdx.x >> 3;
  const int bx = (xcd < r ? xcd * (q + 1) : r * (q + 1) + (xcd - r) * q) + jj;

  const int m0 = (bx >> 1) * 128;
  const int n0 = (bx & 1) * 64;

  f32x4 acc[3][4][2] = {};

  auto stage = [&](int ss) {
    const bool ph1 = (ss < 2);
    #pragma unroll
    for (int i = 0; i < 4; ++i) {
      int unit = w * 256 + i * 64 + lane;
      int row = unit >> 3, x = unit & 7;
      int node = m0 + row; if (node >= n) node = n - 1;
      int xo = (x ^ (row & 7)) << 3;
      const unsigned short* src = ph1
          ? hb   + (size_t)node * FDIM + ss * 64 + xo
          : aggb + (size_t)node * 512 + (ss - 2) * 64 + xo;
      gload16(src, &As[w * 256 + i * 64]);
    }
    const int nsec = ph1 ? 1 : 3;
    for (int s = 0; s < nsec; ++s) {
      int koff = ph1 ? ss * 64 : (FDIM + s * 512 + (ss - 2) * 64);
      #pragma unroll
      for (int i = 0; i < 2; ++i) {
        int unit = w * 128 + i * 64 + lane;
        int row = unit >> 3, x = unit & 7;
        const unsigned short* src =
            wBT + (size_t)(n0 + row) * K + koff + ((x ^ (row & 7)) << 3);
        gload16(src, &Bs[s][w * 128 + i * 64]);
      }
    }
  };

  for (int step = 0; step < NK; ++step) {
    stage(step);
    __syncthreads();
    #pragma unroll
    for (int ks = 0; ks < 2; ++ks) {
      s16x8 a[4];
      #pragma unroll
      for (int m = 0; m < 4; ++m) {
        int row = wr * 64 + m * 16 + lr;
        a[m] = As[row * 8 + ((ks * 4 + hi) ^ rx7)];
      }
      #pragma unroll
      for (int s = 0; s < 3; ++s) {
        if (step < 2 && s > 0) continue;    // h section touches only acc[0]
        int rb = wc * 32 + lr;
        s16x8 b0 = Bs[s][rb * 8 + ((ks * 4 + hi) ^ rx7)];
        s16x8 b1 = Bs[s][(rb + 16) * 8 + ((ks * 4 + hi) ^ rx7)];
        #pragma unroll
        for (int m = 0; m < 4; ++m) {
          acc[s][m][0] = __builtin_amdgcn_mfma_f32_16x16x32_bf16(a[m], b0, acc[s][m][0], 0, 0, 0);
          acc[s][m][1] = __builtin_amdgcn_mfma_f32_16x16x32_bf16(a[m], b1, acc[s][m][1], 0, 0, 0);
        }
      }
    }
    __syncthreads();
  }

  // ---- epilogue: combine, bias, relu, store; fused BN partial sums ----
  float* red = (float*)&As[0];        // 128 floats
  if (t < 128) red[t] = 0.f;
  __syncthreads();

  const float bv0 = bias[n0 + wc * 32 + lr];
  const float bv1 = bias[n0 + wc * 32 + 16 + lr];
  float cs[2] = {0.f, 0.f}, cq[2] = {0.f, 0.f};
  #pragma unroll
  for (int m = 0; m < 4; ++m) {
    #pragma unroll
    for (int i = 0; i < 4; ++i) {
      int grow = m0 + wr * 64 + m * 16 + hi * 4 + i;
      if (grow >= n) continue;
      float2 sv = s12a[grow];
      #pragma unroll
      for (int nn = 0; nn < 2; ++nn) {
        float v = acc[0][m][nn][i] + sv.x * acc[1][m][nn][i] + sv.y * acc[2][m][nn][i]
                + (nn ? bv1 : bv0);
        v = fmaxf(v, 0.f);
        out[(size_t)grow * FDIM + n0 + wc * 32 + nn * 16 + lr] = v;
        cs[nn] += v; cq[nn] += v * v;
      }
    }
  }
  #pragma unroll
  for (int nn = 0; nn < 2; ++nn) {
    int lc = wc * 32 + nn * 16 + lr;
    atomicAdd(&red[lc], cs[nn]);
    atomicAdd(&red[64 + lc], cq[nn]);
  }
  __syncthreads();
  if (t < 64)       atomicAdd(&bnsum[n0 + t], red[t]);
  else if (t < 128) atomicAdd(&bnsq[n0 + t - 64], red[t]);
}

// ---------------- BatchNorm apply ----------------
__global__ void bn_norm(float* __restrict__ out, const float* __restrict__ bnsum,
                        const float* __restrict__ bnsq, const float* __restrict__ gamma,
                        const float* __restrict__ beta, int n) {
  const int j = threadIdx.x & 127;
  const float invN = 1.f / (float)n;
  const float mu = bnsum[j] * invN;
  const float var = bnsq[j] * invN - mu * mu;
  const float rs = rsqrtf(var + BN_EPS);
  const float sc = gamma[j] * rs;
  const float sh = beta[j] - mu * sc;
  const int gt = blockIdx.x * 256 + threadIdx.x;
  const int row0 = gt >> 7;
  const int rstride = (gridDim.x * 256) >> 7;
  for (int i = row0; i < n; i += rstride) {
    size_t idx = (size_t)i * FDIM + j;
    out[idx] = out[idx] * sc + sh;
  }
}

extern "C" void kernel_launch(void* const* d_in, const int* in_sizes, int n_in,
                              void* d_out, int out_size, void* d_ws, size_t ws_size,
                              hipStream_t stream) {
  const float* h     = (const float*)d_in[0];
  const int*   src   = (const int*)d_in[1];
  const int*   dst   = (const int*)d_in[2];
  const float* W     = (const float*)d_in[3];
  const float* bias  = (const float*)d_in[4];
  const float* gamma = (const float*)d_in[5];
  const float* beta  = (const float*)d_in[6];
  float* out = (float*)d_out;

  const int n = in_sizes[0] / FDIM;      // 50000
  const int E = in_sizes[1];             // 650000
  const int K = in_sizes[3] / FDIM;      // 1664

  char* base = (char*)d_ws;
  size_t off = 0;
  auto alloc = [&](size_t bytes) -> void* {
    void* p = base + off;
    off += (bytes + 255) & ~(size_t)255;
    return p;
  };
  int*   deg    = (int*)  alloc(4ull * n);
  int*   cursor = (int*)  alloc(4ull * n);
  float* bnsum  = (float*)alloc(512);
  float* bnsq   = (float*)alloc(512);
  const size_t zlen = off;               // zero deg+cursor+bn each call
  int*    offs  = (int*)  alloc(4ull * (n + 1));
  int*    bsums = (int*)  alloc(4ull * 256);
  int*    csr   = (int*)  alloc(4ull * E);
  float2* s12a  = (float2*)alloc(8ull * n);
  unsigned short* aggb = (unsigned short*)alloc(2ull * (size_t)n * 512);
  unsigned short* wBT  = (unsigned short*)alloc(2ull * (size_t)K * FDIM);
  unsigned short* hb   = (unsigned short*)alloc(2ull * (size_t)n * FDIM);
  (void)ws_size; (void)n_in; (void)out_size;

  const int eb = (E + 255) / 256;
  const int nb = (n + 255) / 256;        // 196 scan blocks (<=256)
  const int w0 = n * FDIM / 8;
  const int w1 = K * FDIM;
  const int w2 = E;

  hipMemsetAsync(d_ws, 0, zlen, stream);
  prep_kernel<<<(w0 + w1 + w2 + 255) / 256, 256, 0, stream>>>(h, hb, W, wBT, dst, deg,
                                                              w0, w1, w2, K);
  scan1<<<nb, 256, 0, stream>>>(deg, offs, bsums, n);
  csr_fill<<<eb, 256, 0, stream>>>(src, dst, offs, bsums, cursor, csr, E, nb);
  agg_kernel<<<(n + 3) / 4, 256, 0, stream>>>(hb, csr, offs, bsums, aggb, s12a, n, E, nb);
  const int gblocks = ((n + 127) / 128) * 2;
  gemm_kernel<<<gblocks, 256, 0, stream>>>(hb, wBT, aggb, s12a, bias,
                                           out, bnsum, bnsq, n, K);
  bn_norm<<<1024, 256, 0, stream>>>(out, bnsum, bnsq, gamma, beta, n);
}